// Round 1
// baseline (1528.872 us; speedup 1.0000x reference)
//
#include <hip/hip_runtime.h>
#include <math.h>

#define WAVES_PER_BLOCK 4
#define BLOCK_SIZE 256

// One wave (64 lanes) per row. C <= 1024, C % 4 == 0 assumed optimal path
// (C=1000). Row of 1000 floats = 250 float4 chunks; lane holds chunks
// {lane, lane+64, lane+128, lane+192} -> 4 float4 regs (16 VGPRs).
__global__ __launch_bounds__(BLOCK_SIZE) void focal_rows(
    const float* __restrict__ pred, const int* __restrict__ labels,
    float* __restrict__ partials, int N, int C) {
  const int lane = threadIdx.x & 63;
  const int wave = threadIdx.x >> 6;
  const int wave_id = blockIdx.x * WAVES_PER_BLOCK + wave;
  const int n_waves = gridDim.x * WAVES_PER_BLOCK;
  const int nchunk = (C + 3) >> 2;  // 250 for C=1000

  float acc = 0.0f;

  for (int row = wave_id; row < N; row += n_waves) {
    const float4* rowp = (const float4*)(pred + (size_t)row * (size_t)C);

    float4 v[4];
#pragma unroll
    for (int it = 0; it < 4; ++it) {
      const int j = lane + (it << 6);
      if (j < nchunk) {
        float4 t = rowp[j];
        const int rem = C - (j << 2);      // elements valid in this chunk
        if (rem < 4) t.w = -INFINITY;       // generic tail mask (never hit at C=1000)
        if (rem < 3) t.z = -INFINITY;
        if (rem < 2) t.y = -INFINITY;
        v[it] = t;
      } else {
        v[it] = make_float4(-INFINITY, -INFINITY, -INFINITY, -INFINITY);
      }
    }

    // ---- local top-2 over this lane's 16 elements (branchless) ----
    float m1 = -INFINITY, m2 = -INFINITY;
#pragma unroll
    for (int it = 0; it < 4; ++it) {
      const float xs[4] = {v[it].x, v[it].y, v[it].z, v[it].w};
#pragma unroll
      for (int k = 0; k < 4; ++k) {
        const float x = xs[k];
        m2 = fmaxf(m2, fminf(m1, x));
        m1 = fmaxf(m1, x);
      }
    }
    // ---- 64-lane butterfly top-2 merge ----
#pragma unroll
    for (int off = 32; off > 0; off >>= 1) {
      const float o1 = __shfl_xor(m1, off, 64);
      const float o2 = __shfl_xor(m2, off, 64);
      const float nm2 = fmaxf(fmaxf(m2, o2), fminf(m1, o1));
      m1 = fmaxf(m1, o1);
      m2 = nm2;
    }

    // ---- sum of exp(x - m1) ----
    float s = 0.0f;
#pragma unroll
    for (int it = 0; it < 4; ++it) {
      s += __expf(v[it].x - m1);
      s += __expf(v[it].y - m1);
      s += __expf(v[it].z - m1);
      s += __expf(v[it].w - m1);
    }
#pragma unroll
    for (int off = 32; off > 0; off >>= 1) s += __shfl_xor(s, off, 64);

    // ---- label logit (label is wave-uniform) ----
    const int label = labels[row];
    const int j = label >> 2;
    const int src = j & 63;
    const int it = j >> 6;         // wave-uniform
    const int comp = label & 3;    // wave-uniform
    const float4 vv = (it == 0) ? v[0] : (it == 1) ? v[1] : (it == 2) ? v[2] : v[3];
    float xl = (comp == 0) ? vv.x : (comp == 1) ? vv.y : (comp == 2) ? vv.z : vv.w;
    xl = __shfl(xl, src, 64);

    // ---- loss term ----
    // top1 prob = 1/Z, top2 prob = exp(m2-m1)/Z, p = exp(xl-m1)/Z
    const float logZ = __logf(s);
    const float logp = (xl - m1) - logZ;
    const float p = __expf(logp);
    const float diff = (1.0f - __expf(m2 - m1)) / s;
    const float y = 3.0f * diff;
    float w;
    if (y <= 0.01f) w = 1.0f;                 // y thresholded to 0 -> (1-p)^0 = 1
    else w = __powf(fmaxf(1.0f - p, 0.0f), y);
    acc -= w * logp;
  }

  // ---- block reduce (lane 0 per wave already holds the full wave sum
  //      since acc is identical across lanes only for the reduced parts;
  //      acc itself is lane-uniform because all inputs to it are post-reduce) ----
  __shared__ float lds[WAVES_PER_BLOCK];
  if (lane == 0) lds[wave] = acc;
  __syncthreads();
  if (threadIdx.x == 0) {
    float t = 0.0f;
#pragma unroll
    for (int i = 0; i < WAVES_PER_BLOCK; ++i) t += lds[i];
    partials[blockIdx.x] = t;
  }
}

__global__ __launch_bounds__(BLOCK_SIZE) void reduce_partials(
    const float* __restrict__ partials, int n, float* __restrict__ out,
    double inv_n) {
  double t = 0.0;
  for (int i = threadIdx.x; i < n; i += BLOCK_SIZE) t += (double)partials[i];
#pragma unroll
  for (int off = 32; off > 0; off >>= 1) t += __shfl_xor(t, off, 64);
  __shared__ double lds[WAVES_PER_BLOCK];
  const int lane = threadIdx.x & 63;
  const int wave = threadIdx.x >> 6;
  if (lane == 0) lds[wave] = t;
  __syncthreads();
  if (threadIdx.x == 0) {
    double tot = 0.0;
#pragma unroll
    for (int i = 0; i < WAVES_PER_BLOCK; ++i) tot += lds[i];
    out[0] = (float)(tot * inv_n);
  }
}

extern "C" void kernel_launch(void* const* d_in, const int* in_sizes, int n_in,
                              void* d_out, int out_size, void* d_ws, size_t ws_size,
                              hipStream_t stream) {
  const float* pred = (const float*)d_in[0];
  const int* labels = (const int*)d_in[1];
  float* out = (float*)d_out;

  const int N = in_sizes[1];            // 262144
  const int C = in_sizes[0] / N;        // 1000

  int nblocks = 8192;
  const int max_partials = (int)(ws_size / sizeof(float));
  if (nblocks > max_partials) nblocks = max_partials;

  float* partials = (float*)d_ws;

  focal_rows<<<nblocks, BLOCK_SIZE, 0, stream>>>(pred, labels, partials, N, C);
  reduce_partials<<<1, BLOCK_SIZE, 0, stream>>>(partials, nblocks, out,
                                                1.0 / (double)N);
}